// Round 3
// baseline (31.385 us; speedup 1.0000x reference)
//
#include <hip/hip_runtime.h>

#define HH 224
#define WW 224
#define K 15
#define PAD 7
#define BX 32
#define BY 8
#define TW (BX + K - 1)   /* 46 */
#define TH (BY + K - 1)   /* 22 */
#define TSTRIDE 48        /* even: keeps row bases 8B-aligned; bank shift 16/row -> 2-way (free) */

__global__ __launch_bounds__(BX * BY)
void bilateral_denoise_kernel(const float* __restrict__ x,
                              const float* __restrict__ blur_sigma_p,
                              const float* __restrict__ diff_sigma_p,
                              float* __restrict__ out)
{
    __shared__ __align__(16) float tile[TH * TSTRIDE];

    const int tx = threadIdx.x;           // 0..31
    const int ty = threadIdx.y;           // 0..7
    const int tid = ty * BX + tx;
    const int w0 = blockIdx.x * BX;
    const int h0 = blockIdx.y * BY;
    const int plane = blockIdx.z;         // b*C + c, 0..5

    const float* __restrict__ xp = x + (size_t)plane * HH * WW;

    // ---- stage halo tile (boundary -> -100, matching constant pad) ----
    for (int idx = tid; idx < TH * TW; idx += BX * BY) {
        const int r = idx / TW;
        const int c = idx - r * TW;
        const int gh = h0 - PAD + r;
        const int gw = w0 - PAD + c;
        float v = -100.0f;
        if (gh >= 0 && gh < HH && gw >= 0 && gw < WW) v = xp[gh * WW + gw];
        tile[r * TSTRIDE + c] = v;
    }
    __syncthreads();

    const float bs = blur_sigma_p[0];
    const float ds = diff_sigma_p[0];
    const float LOG2E = 1.44269504088896340736f;
    const float na  = -LOG2E / (ds * ds);   // scale on (v-cv)^2
    const float nk2 = -LOG2E / (bs * bs);   // scale on spatial squared distance

    const float cv = tile[(ty + PAD) * TSTRIDE + tx + PAD];
    // na*(v-cv)^2 = na*v^2 + bb*v + cc
    const float bb = -2.0f * na * cv;
    const float cc = na * cv * cv;

    const int ecol = tx & ~1;   // even base column for 8B-aligned float2 reads
    const int par  = tx & 1;    // parity: value at slot k has window offset j = k - par

    // 16 per-column-slot accumulators; column spatial weight applied in finale
    float colw[16];
    float colv[16];
#pragma unroll
    for (int k = 0; k < 16; ++k) { colw[k] = 0.0f; colv[k] = 0.0f; }

#pragma unroll
    for (int i = 0; i < K; ++i) {
        // fold the row spatial term into the constant: ci = cc + (i-PAD)^2 * nk2
        const float ci = __builtin_fmaf((float)((i - PAD) * (i - PAD)), nk2, cc);
        const float2* __restrict__ rp =
            (const float2*)&tile[(ty + i) * TSTRIDE + ecol];
        float2 r[8];
#pragma unroll
        for (int q = 0; q < 8; ++q) r[q] = rp[q];   // 8x ds_read_b64 (vs 15x b32)
#pragma unroll
        for (int k = 0; k < 16; ++k) {
            const float v = (k & 1) ? r[k >> 1].y : r[k >> 1].x;
            const float inner = __builtin_fmaf(v, na, bb);   // na*v + bb
            const float t = __builtin_fmaf(v, inner, ci);    // na*v^2 + bb*v + ci
            const float e = __builtin_amdgcn_exp2f(t);
            colw[k] += e;
            colv[k] = __builtin_fmaf(e, v, colv[k]);
        }
    }

    // finale: column spatial weights; out-of-window slot (j<0 or j>14) gets 0
    float wsum = 0.0f;
    float vsum = 0.0f;
#pragma unroll
    for (int k = 0; k < 16; ++k) {
        const int j = k - par;                  // window column offset, -1..15
        const float wj = (j < 0 || j > 14)
            ? 0.0f
            : __builtin_amdgcn_exp2f((float)((j - PAD) * (j - PAD)) * nk2);
        wsum = __builtin_fmaf(wj, colw[k], wsum);
        vsum = __builtin_fmaf(wj, colv[k], vsum);
    }

    out[(size_t)plane * HH * WW + (size_t)(h0 + ty) * WW + (w0 + tx)] = vsum / wsum;
}

extern "C" void kernel_launch(void* const* d_in, const int* in_sizes, int n_in,
                              void* d_out, int out_size, void* d_ws, size_t ws_size,
                              hipStream_t stream) {
    const float* x  = (const float*)d_in[0];
    const float* bs = (const float*)d_in[1];
    const float* ds = (const float*)d_in[2];
    float* out = (float*)d_out;

    const int planes = in_sizes[0] / (HH * WW);   // B*C = 6
    dim3 grid(WW / BX, HH / BY, planes);          // 7 x 28 x 6 = 1176 blocks
    dim3 block(BX, BY, 1);
    hipLaunchKernelGGL(bilateral_denoise_kernel, grid, block, 0, stream,
                       x, bs, ds, out);
}

// Round 4
// 21.219 us; speedup vs baseline: 1.4791x; 1.4791x over previous
//
#include <hip/hip_runtime.h>

#define HH 224
#define WW 224
#define K 15
#define PAD 7
#define BX 32
#define BYO 4              /* output rows per block */
#define TW (BX + K - 1)    /* 46 */
#define TH2 (BYO + K - 1)  /* 18 staged rows */
#define TSTRIDE 48         /* bank shift 16/row -> 2-way aliasing (free) */

__global__ __launch_bounds__(BX * 8)
void bilateral_denoise_kernel(const float* __restrict__ x,
                              const float* __restrict__ blur_sigma_p,
                              const float* __restrict__ diff_sigma_p,
                              float* __restrict__ out)
{
    __shared__ float tile[TH2 * TSTRIDE];
    __shared__ float pw[256];
    __shared__ float pv[256];

    const int tx   = threadIdx.x;        // 0..31
    const int ty   = threadIdx.y;        // 0..7
    const int tid  = ty * BX + tx;
    const int tyo  = ty & 3;             // output row within tile
    const int half = ty >> 2;            // 0: window rows 0..7, 1: rows 8..14
    const int w0 = blockIdx.x * BX;
    const int h0 = blockIdx.y * BYO;
    const int plane = blockIdx.z;        // b*C + c, 0..5

    const float* __restrict__ xp = x + (size_t)plane * HH * WW;

    // ---- stage 18x46 halo tile, no integer div (boundary -> -100) ----
    for (int rr = ty; rr < TH2; rr += 8) {
        const int gh = h0 - PAD + rr;
        for (int cc = tx; cc < TW; cc += BX) {
            const int gw = w0 - PAD + cc;
            float v = -100.0f;
            if (gh >= 0 && gh < HH && gw >= 0 && gw < WW) v = xp[gh * WW + gw];
            tile[rr * TSTRIDE + cc] = v;
        }
    }
    __syncthreads();

    const float bs = blur_sigma_p[0];
    const float ds = diff_sigma_p[0];
    const float LOG2E = 1.44269504088896340736f;
    const float na  = -LOG2E / (ds * ds);
    const float nk2 = -LOG2E / (bs * bs);

    const float cv = tile[(tyo + PAD) * TSTRIDE + tx + PAD];
    // na*(v-cv)^2 = na*v^2 + bb*v + cc2
    const float bb  = -2.0f * na * cv;
    const float cc2 = na * cv * cv;

    float colw[K];
    float colv[K];
#pragma unroll
    for (int j = 0; j < K; ++j) { colw[j] = 0.0f; colv[j] = 0.0f; }

    // ---- half the window rows per thread-group (wave-uniform branch) ----
    if (half == 0) {
#pragma unroll
        for (int i = 0; i < 8; ++i) {
            const float ci = __builtin_fmaf((float)((i - PAD) * (i - PAD)), nk2, cc2);
            const float* __restrict__ row = &tile[(tyo + i) * TSTRIDE + tx];
#pragma unroll
            for (int j = 0; j < K; ++j) {
                const float v = row[j];
                const float inner = __builtin_fmaf(v, na, bb);
                const float t = __builtin_fmaf(v, inner, ci);
                const float e = __builtin_amdgcn_exp2f(t);
                colw[j] += e;
                colv[j] = __builtin_fmaf(e, v, colv[j]);
            }
        }
    } else {
#pragma unroll
        for (int ii = 0; ii < 7; ++ii) {
            const int i = 8 + ii;
            const float ci = __builtin_fmaf((float)((i - PAD) * (i - PAD)), nk2, cc2);
            const float* __restrict__ row = &tile[(tyo + i) * TSTRIDE + tx];
#pragma unroll
            for (int j = 0; j < K; ++j) {
                const float v = row[j];
                const float inner = __builtin_fmaf(v, na, bb);
                const float t = __builtin_fmaf(v, inner, ci);
                const float e = __builtin_amdgcn_exp2f(t);
                colw[j] += e;
                colv[j] = __builtin_fmaf(e, v, colv[j]);
            }
        }
    }

    // fold column spatial weights
    float wsum = 0.0f;
    float vsum = 0.0f;
#pragma unroll
    for (int j = 0; j < K; ++j) {
        const float wj = __builtin_amdgcn_exp2f((float)((j - PAD) * (j - PAD)) * nk2);
        wsum = __builtin_fmaf(wj, colw[j], wsum);
        vsum = __builtin_fmaf(wj, colv[j], vsum);
    }

    pw[tid] = wsum;
    pv[tid] = vsum;
    __syncthreads();

    // ---- combine the two row-halves, write 32x4 outputs ----
    if (ty < BYO) {
        const float w = pw[tid] + pw[tid + 128];
        const float v = pv[tid] + pv[tid + 128];
        out[(size_t)plane * HH * WW + (size_t)(h0 + ty) * WW + (w0 + tx)] = v / w;
    }
}

extern "C" void kernel_launch(void* const* d_in, const int* in_sizes, int n_in,
                              void* d_out, int out_size, void* d_ws, size_t ws_size,
                              hipStream_t stream) {
    const float* x  = (const float*)d_in[0];
    const float* bs = (const float*)d_in[1];
    const float* ds = (const float*)d_in[2];
    float* out = (float*)d_out;

    const int planes = in_sizes[0] / (HH * WW);     // B*C = 6
    dim3 grid(WW / BX, HH / BYO, planes);           // 7 x 56 x 6 = 2352 blocks
    dim3 block(BX, 8, 1);
    hipLaunchKernelGGL(bilateral_denoise_kernel, grid, block, 0, stream,
                       x, bs, ds, out);
}